// Round 10
// baseline (186.043 us; speedup 1.0000x reference)
//
#include <hip/hip_runtime.h>

#pragma clang fp contract(off)

#define NB 32
#define NP 2048
#define NT 128
#define BIGF 1e30f

// Exact replication of the reference cost formula (float32, no FMA contraction).
__device__ __forceinline__ float box_cost(float ox0, float oy0, float ox1, float oy1,
                                          float tx0, float ty0, float tx1, float ty1,
                                          float area1, float area2) {
    float l1 = ((fabsf(ox0 - tx0) + fabsf(oy0 - ty0)) + fabsf(ox1 - tx1)) + fabsf(oy1 - ty1);
    float ltx = fmaxf(ox0, tx0), lty = fmaxf(oy0, ty0);
    float rbx = fminf(ox1, tx1), rby = fminf(oy1, ty1);
    float wx = fmaxf(rbx - ltx, 0.0f), wy = fmaxf(rby - lty, 0.0f);
    float inter = wx * wy;
    float uni = (area1 + area2) - inter;
    float iou = inter / (uni + 1e-8f);
    float ex = fmaxf(fmaxf(ox1, tx1) - fminf(ox0, tx0), 0.0f);
    float ey = fmaxf(fmaxf(oy1, ty1) - fminf(oy0, ty0), 0.0f);
    float earea = ex * ey;
    float giou = iou - (earea - uni) / (earea + 1e-8f);
    return l1 - giou;
}

// Phase 1: cost_T[b][t][p] (rows = targets, cols = preds), [NB][NT][NP] f32.
// XCD-aware block remap (kept from R8).
__global__ __launch_bounds__(256) void cost_kernel(const float* __restrict__ ob,
                                                   const float* __restrict__ tb,
                                                   float* __restrict__ cost) {
    int m = blockIdx.x;
    int x = m & 7;
    int q = m >> 3;
    int b = x + 8 * (q >> 10);
    int inner = q & 1023;
    int ofs = inner * 256 + (int)threadIdx.x;
    int t = ofs >> 11;
    int p = ofs & (NP - 1);
    float4 o = ((const float4*)ob)[b * NP + p];
    float4 g = ((const float4*)tb)[b * NT + t];
    float a1 = (o.z - o.x) * (o.w - o.y);
    float a2 = (g.z - g.x) * (g.w - g.y);
    cost[(size_t)b * NT * NP + ofs] = box_cost(o.x, o.y, o.z, o.w, g.x, g.y, g.z, g.w, a1, a2);
}

// ---- DPP wave-wide argmin: value-only v_min DPP chain, then ballot+readlane
// for the index. First-index tie-break exact: within-lane ties resolved by the
// em/ctz local recovery; cross-lane ties (popcount>1, rare) by min-column scan.
#define DPP_ROW_SHR(n) (0x110 | (n))
#define DPP_BCAST15 0x142
#define DPP_BCAST31 0x143

template <int CTRL>
__device__ __forceinline__ float vmin_step(float v) {
    int s = __builtin_amdgcn_update_dpp(0x7149F2CA /* 1e30f */, __float_as_int(v),
                                        CTRL, 0xF, 0xF, false);
    return fminf(v, __int_as_float(s));
}

__device__ __forceinline__ void wave_argmin(float& bv, int& bj) {
    float m = bv;
    m = vmin_step<DPP_ROW_SHR(1)>(m);
    m = vmin_step<DPP_ROW_SHR(2)>(m);
    m = vmin_step<DPP_ROW_SHR(4)>(m);
    m = vmin_step<DPP_ROW_SHR(8)>(m);
    m = vmin_step<DPP_BCAST15>(m);
    m = vmin_step<DPP_BCAST31>(m);
    float g = __int_as_float(__builtin_amdgcn_readlane(__float_as_int(m), 63));
    unsigned long long win = __ballot(bv == g);
    int L = __ffsll((unsigned long long)win) - 1;
    int j = __builtin_amdgcn_readlane(bj, L);
    if (__builtin_popcountll(win) > 1) {   // exact cross-lane tie-break (rare)
        unsigned long long w = win & (win - 1);
        while (w) {
            int l = __ffsll((unsigned long long)w) - 1; w &= w - 1;
            int cj = __builtin_amdgcn_readlane(bj, l);
            j = (cj < j) ? cj : j;
        }
    }
    bv = g; bj = j;
}

// Assigned-check without LDS: bit sl of owner lane ow's asg mask, via ballot.
#define ASG_CHECK(ow, sl) (__ballot((lane == (ow)) && ((asg >> (sl)) & 1u)) != 0ull)

// Value-only local min tree over 32 per-slot expressions EXPR(s), then
// equality-mask + ctz index recovery (shallow, overlaps the DPP chain).
// Produces: bv = local min value, bj = smallest column j with that value.
#define LOCAL_ARGMIN(EXPR)                                                     \
    {                                                                          \
        float q0 = fminf(fminf(EXPR(0), EXPR(1)), fminf(EXPR(2), EXPR(3)));    \
        float q1 = fminf(fminf(EXPR(4), EXPR(5)), fminf(EXPR(6), EXPR(7)));    \
        float q2 = fminf(fminf(EXPR(8), EXPR(9)), fminf(EXPR(10), EXPR(11)));  \
        float q3 = fminf(fminf(EXPR(12), EXPR(13)), fminf(EXPR(14), EXPR(15)));\
        float q4 = fminf(fminf(EXPR(16), EXPR(17)), fminf(EXPR(18), EXPR(19)));\
        float q5 = fminf(fminf(EXPR(20), EXPR(21)), fminf(EXPR(22), EXPR(23)));\
        float q6 = fminf(fminf(EXPR(24), EXPR(25)), fminf(EXPR(26), EXPR(27)));\
        float q7 = fminf(fminf(EXPR(28), EXPR(29)), fminf(EXPR(30), EXPR(31)));\
        float h0 = fminf(q0, q1), h1 = fminf(q2, q3);                          \
        float h2 = fminf(q4, q5), h3 = fminf(q6, q7);                          \
        bv = fminf(fminf(h0, h1), fminf(h2, h3));                              \
        unsigned em = 0u;                                                      \
        _Pragma("unroll") for (int s = 0; s < 32; ++s)                         \
            em |= (EXPR(s) == bv) ? (1u << s) : 0u;                            \
        int ls = __builtin_ctz(em);                                            \
        bj = (((ls >> 2) << 8) | (ls & 3)) | lane4;                            \
    }

#define E_FAST(s) spc_r[s]
#define E_GEN(s) (((SCm >> (s)) & 1u) ? BIGF : spc_r[s])

// Row body: consumes CUR (row I's costs), prefetches row I+1 into NXT at start.
#define ROW_BODY(I, CUR, NXT)                                                          \
  {                                                                                    \
    const int i = (I);                                                                 \
    if (i + 1 < NT) {                                                                  \
        const float4* nrow = (const float4*)(costb + (size_t)(i + 1) * NP);            \
        _Pragma("unroll") for (int g = 0; g < 8; ++g) {                                \
            float4 t4 = nrow[g * 64 + lane];                                           \
            NXT[g * 4 + 0] = t4.x; NXT[g * 4 + 1] = t4.y;                              \
            NXT[g * 4 + 2] = t4.z; NXT[g * 4 + 3] = t4.w;                              \
        }                                                                              \
    }                                                                                  \
    unsigned SCm = 0, pathm = 0;                                                       \
    int sr01 = 0;                                                                      \
    /* ---- fast first pop: cur=i, minv=0, u[i]=0 -> red = cost - v exactly ---- */    \
    float bv; int bj;                                                                  \
    _Pragma("unroll") for (int s = 0; s < 32; ++s) spc_r[s] = CUR[s] - v_r[s];         \
    LOCAL_ARGMIN(E_FAST)                                                               \
    wave_argmin(bv, bj);                                                               \
    float mv = bv; int mj = bj;                                                        \
    int ow0 = (mj >> 2) & 63;                                                          \
    int sl0 = ((mj >> 8) << 2) | (mj & 3);                                             \
    if (lane == ow0) SCm |= (1u << sl0);                                               \
    int npops = 1;                                                                     \
    bool assigned = ASG_CHECK(ow0, sl0);                                               \
    if (assigned) {                                                                    \
        int r = row4col[mj];                                                           \
        /* ---- general shortest-path continuation ---- */                             \
        for (;;) {                                                                     \
            if ((r & 63) == lane) {                                                    \
                if (r < 64) { sr01 |= 1; pm0 = mv; }                                   \
                else        { sr01 |= 2; pm1 = mv; }                                   \
            }                                                                          \
            const int cur = r;                                                         \
            float usel = (cur >= 64) ? u1 : u0;                                        \
            float ucur = __int_as_float(                                               \
                __builtin_amdgcn_readlane(__float_as_int(usel), cur & 63));            \
            const float4* rrow = (const float4*)(costb + (size_t)cur * NP);            \
            _Pragma("unroll") for (int g = 0; g < 8; ++g) {                            \
                float4 t4 = rrow[g * 64 + lane];                                       \
                cr[g * 4 + 0] = t4.x; cr[g * 4 + 1] = t4.y;                            \
                cr[g * 4 + 2] = t4.z; cr[g * 4 + 3] = t4.w;                            \
            }                                                                          \
            _Pragma("unroll") for (int s = 0; s < 32; ++s) {                           \
                float red = ((mv + cr[s]) - ucur) - v_r[s];                            \
                bool notSC = ((SCm >> s) & 1u) == 0u;                                  \
                bool imp = notSC && (red < spc_r[s]);                                  \
                spc_r[s] = imp ? red : spc_r[s];                                       \
                path_r[s] = imp ? cur : path_r[s];                                     \
                pathm = imp ? (pathm | (1u << s)) : pathm;                             \
            }                                                                          \
            LOCAL_ARGMIN(E_GEN)                                                        \
            wave_argmin(bv, bj);                                                       \
            mv = bv; mj = bj;                                                          \
            ow0 = (mj >> 2) & 63; sl0 = ((mj >> 8) << 2) | (mj & 3);                   \
            if (lane == ow0) SCm |= (1u << sl0);                                       \
            ++npops;                                                                   \
            assigned = ASG_CHECK(ow0, sl0);                                            \
            if (!assigned) break;                                                      \
            r = row4col[mj];                                                           \
        }                                                                              \
    }                                                                                  \
    const int sink = mj;                                                               \
    const float minv = mv;                                                             \
    /* sink becomes assigned: register mask mirrors row4col[sink]>=0 */                \
    if (lane == ow0) asg |= (1u << sl0);                                               \
    /* ---- dual v update (exact reference op, SCm-masked; 1 bit if npops==1) */       \
    _Pragma("unroll") for (int s = 0; s < 32; ++s) {                                   \
        if ((SCm >> s) & 1u) v_r[s] = (v_r[s] + spc_r[s]) - minv;                      \
    }                                                                                  \
    /* ---- u updates (exact reference order; off next-row critical path) ---- */      \
    if ((i & 63) == lane) { if (i < 64) u0 = u0 + minv; else u1 = u1 + minv; }         \
    if (sr01 & 1) u0 = (u0 + minv) - pm0;                                              \
    if (sr01 & 2) u1 = (u1 + minv) - pm1;                                              \
    if (npops == 1) {                                                                  \
        if (lane == 0) { row4col[sink] = i; col4row[i] = sink; }                       \
    } else {                                                                           \
        int j = sink;                                                                  \
        while (true) {                                                                 \
            int sl = ((j >> 8) << 2) | (j & 3);                                        \
            int ow = (j >> 2) & 63;                                                    \
            int pv = ((pathm >> 0) & 1u) ? path_r[0] : i;                              \
            _Pragma("unroll") for (int s = 1; s < 32; ++s) {                           \
                int leaf = ((pathm >> s) & 1u) ? path_r[s] : i;                        \
                pv = (sl == s) ? leaf : pv;                                            \
            }                                                                          \
            int ii = __builtin_amdgcn_readlane(pv, ow);                                \
            if (lane == 0) row4col[j] = ii;                                            \
            int nj = col4row[ii];                                                      \
            if (lane == 0) col4row[ii] = j;                                            \
            if (ii == i) break;                                                        \
            j = nj;                                                                    \
        }                                                                              \
    }                                                                                  \
  }

// Phase 2: wave-synchronous JV LSAP. One 64-lane wave per batch.
// Column j: owner lane = (j>>2)&63, slot = ((j>>8)<<2)|(j&3).
__global__ __launch_bounds__(64) void solve_wave(const float* __restrict__ cost,
                                                 int* __restrict__ out) {
    __shared__ int row4col[NP];
    __shared__ int col4row[NT];

    const int lane = threadIdx.x;
    const int lane4 = lane << 2;
    const int b = blockIdx.x;
    const float* costb = cost + (size_t)b * NT * NP;

    float pfA[32], pfB[32], v_r[32], spc_r[32], cr[32];
    int path_r[32];
    unsigned asg = 0;   // per-lane assigned-column bitmask (slot s of this lane)
    float u0 = 0.0f, u1 = 0.0f, pm0 = 0.0f, pm1 = 0.0f;

#pragma unroll
    for (int s = 0; s < 32; ++s) { v_r[s] = 0.0f; path_r[s] = 0; }
    for (int j = lane; j < NP; j += 64) row4col[j] = -1;
    col4row[lane] = -1;
    col4row[lane + 64] = -1;

    {   // prefetch row 0 into pfA
        const float4* r0 = (const float4*)costb;
#pragma unroll
        for (int g = 0; g < 8; ++g) {
            float4 t4 = r0[g * 64 + lane];
            pfA[g * 4 + 0] = t4.x; pfA[g * 4 + 1] = t4.y;
            pfA[g * 4 + 2] = t4.z; pfA[g * 4 + 3] = t4.w;
        }
    }

    for (int ih = 0; ih < NT / 2; ++ih) {
        ROW_BODY(2 * ih, pfA, pfB)
        ROW_BODY(2 * ih + 1, pfB, pfA)
    }

    // output: sort targets by assigned pred index (all distinct)
    for (int t = lane; t < NT; t += 64) {
        int c = col4row[t];
        int rank = 0;
        for (int t2 = 0; t2 < NT; ++t2) rank += (col4row[t2] < c) ? 1 : 0;
        out[(b * 2 + 0) * NT + rank] = c;
        out[(b * 2 + 1) * NT + rank] = t;
    }
}

// Fallback (ws too small): LDS-based block solver computing costs on the fly.
__global__ __launch_bounds__(512) void solve_fallback(const float* __restrict__ ob,
                                                      const float* __restrict__ tb,
                                                      int* __restrict__ out) {
    __shared__ float v[NP], spc[NP];
    __shared__ int path[NP], row4col[NP];
    __shared__ unsigned char SC[NP];
    __shared__ float u[NT];
    __shared__ int col4row[NT];
    __shared__ unsigned char SR[NT];
    __shared__ float rv[8];
    __shared__ int ri[8];
    __shared__ int s_cur, s_sink;
    __shared__ float s_minv;
    __shared__ float px0[NP], py0[NP], px1[NP], py1[NP], pa[NP];
    __shared__ float tx0[NT], ty0[NT], tx1[NT], ty1[NT], ta[NT];

    const int tid = threadIdx.x;
    const int b = blockIdx.x;

    for (int j = tid; j < NP; j += 512) {
        v[j] = 0.0f; row4col[j] = -1;
        float4 o = ((const float4*)ob)[b * NP + j];
        px0[j] = o.x; py0[j] = o.y; px1[j] = o.z; py1[j] = o.w;
        pa[j] = (o.z - o.x) * (o.w - o.y);
    }
    for (int t = tid; t < NT; t += 512) {
        u[t] = 0.0f; col4row[t] = -1;
        float4 g = ((const float4*)tb)[b * NT + t];
        tx0[t] = g.x; ty0[t] = g.y; tx1[t] = g.z; ty1[t] = g.w;
        ta[t] = (g.z - g.x) * (g.w - g.y);
    }
    __syncthreads();

    for (int i = 0; i < NT; ++i) {
        for (int j = tid; j < NP; j += 512) { spc[j] = BIGF; SC[j] = 0; }
        for (int t = tid; t < NT; t += 512) SR[t] = 0;
        if (tid == 0) { s_cur = i; s_minv = 0.0f; s_sink = -1; }
        __syncthreads();

        while (s_sink < 0) {
            const int cur = s_cur;
            const float minv = s_minv;
            if (tid == 0) SR[cur] = 1;
            const float ucur = u[cur];
            float c0 = tx0[cur], c1 = ty0[cur], c2 = tx1[cur], c3 = ty1[cur], ca = ta[cur];
            float bv = BIGF;
            int bi = NP;
            for (int k = 0; k < NP / 512; ++k) {
                int j = tid + k * 512;
                float cj = box_cost(px0[j], py0[j], px1[j], py1[j], c0, c1, c2, c3, pa[j], ca);
                float cand;
                if (!SC[j]) {
                    float red = ((minv + cj) - ucur) - v[j];
                    if (red < spc[j]) { spc[j] = red; path[j] = cur; }
                    cand = spc[j];
                } else {
                    cand = BIGF;
                }
                if (cand < bv || (cand == bv && j < bi)) { bv = cand; bi = j; }
            }
            for (int off = 32; off >= 1; off >>= 1) {
                float ov = __shfl_xor(bv, off);
                int oi = __shfl_xor(bi, off);
                if (ov < bv || (ov == bv && oi < bi)) { bv = ov; bi = oi; }
            }
            if ((tid & 63) == 0) { rv[tid >> 6] = bv; ri[tid >> 6] = bi; }
            __syncthreads();
            if (tid == 0) {
                float mvv = rv[0]; int mjj = ri[0];
                for (int w = 1; w < 8; ++w)
                    if (rv[w] < mvv || (rv[w] == mvv && ri[w] < mjj)) { mvv = rv[w]; mjj = ri[w]; }
                s_minv = mvv;
                SC[mjj] = 1;
                int rr = row4col[mjj];
                if (rr < 0) s_sink = mjj; else s_cur = rr;
            }
            __syncthreads();
        }

        const float minv = s_minv;
        const int sink = s_sink;
        for (int j = tid; j < NP; j += 512) if (SC[j]) v[j] = (v[j] + spc[j]) - minv;
        for (int t = tid; t < NT; t += 512) {
            if (t == i) u[t] = u[t] + minv;
            else if (SR[t]) u[t] = (u[t] + minv) - spc[col4row[t]];
        }
        __syncthreads();
        if (tid == 0) {
            int j = sink;
            while (true) {
                int ii = path[j];
                row4col[j] = ii;
                int nj = col4row[ii];
                col4row[ii] = j;
                if (ii == i) break;
                j = nj;
            }
        }
        __syncthreads();
    }

    if (tid < NT) {
        int c = col4row[tid];
        int rank = 0;
        for (int t2 = 0; t2 < NT; ++t2) rank += (col4row[t2] < c) ? 1 : 0;
        out[(b * 2 + 0) * NT + rank] = c;
        out[(b * 2 + 1) * NT + rank] = tid;
    }
}

extern "C" void kernel_launch(void* const* d_in, const int* in_sizes, int n_in,
                              void* d_out, int out_size, void* d_ws, size_t ws_size,
                              hipStream_t stream) {
    const float* ob = (const float*)d_in[0];   // [32, 2048, 4] f32
    const float* tb = (const float*)d_in[1];   // [32, 128, 4] f32
    int* out = (int*)d_out;                    // [32, 2, 128] int32

    const size_t need = (size_t)NB * NT * NP * sizeof(float);  // 32 MB
    if (ws_size >= need) {
        float* cost = (float*)d_ws;
        cost_kernel<<<(NB * NT * NP) / 256, 256, 0, stream>>>(ob, tb, cost);
        solve_wave<<<NB, 64, 0, stream>>>(cost, out);
    } else {
        solve_fallback<<<NB, 512, 0, stream>>>(ob, tb, out);
    }
}

// Round 11
// 158.564 us; speedup vs baseline: 1.1733x; 1.1733x over previous
//
#include <hip/hip_runtime.h>

#pragma clang fp contract(off)

#define NB 32
#define NP 2048
#define NT 128
#define BIGF 1e30f

// Exact replication of the reference cost formula (float32, no FMA contraction).
__device__ __forceinline__ float box_cost(float ox0, float oy0, float ox1, float oy1,
                                          float tx0, float ty0, float tx1, float ty1,
                                          float area1, float area2) {
    float l1 = ((fabsf(ox0 - tx0) + fabsf(oy0 - ty0)) + fabsf(ox1 - tx1)) + fabsf(oy1 - ty1);
    float ltx = fmaxf(ox0, tx0), lty = fmaxf(oy0, ty0);
    float rbx = fminf(ox1, tx1), rby = fminf(oy1, ty1);
    float wx = fmaxf(rbx - ltx, 0.0f), wy = fmaxf(rby - lty, 0.0f);
    float inter = wx * wy;
    float uni = (area1 + area2) - inter;
    float iou = inter / (uni + 1e-8f);
    float ex = fmaxf(fmaxf(ox1, tx1) - fminf(ox0, tx0), 0.0f);
    float ey = fmaxf(fmaxf(oy1, ty1) - fminf(oy0, ty0), 0.0f);
    float earea = ex * ey;
    float giou = iou - (earea - uni) / (earea + 1e-8f);
    return l1 - giou;
}

// Phase 1: cost_T[b][t][p] (rows = targets, cols = preds), [NB][NT][NP] f32.
// XCD-aware block remap (kept from R8).
__global__ __launch_bounds__(256) void cost_kernel(const float* __restrict__ ob,
                                                   const float* __restrict__ tb,
                                                   float* __restrict__ cost) {
    int m = blockIdx.x;
    int x = m & 7;
    int q = m >> 3;
    int b = x + 8 * (q >> 10);
    int inner = q & 1023;
    int ofs = inner * 256 + (int)threadIdx.x;
    int t = ofs >> 11;
    int p = ofs & (NP - 1);
    float4 o = ((const float4*)ob)[b * NP + p];
    float4 g = ((const float4*)tb)[b * NT + t];
    float a1 = (o.z - o.x) * (o.w - o.y);
    float a2 = (g.z - g.x) * (g.w - g.y);
    cost[(size_t)b * NT * NP + ofs] = box_cost(o.x, o.y, o.z, o.w, g.x, g.y, g.z, g.w, a1, a2);
}

// ---- DPP wave-wide argmin: value-only v_min DPP chain, then ballot+readlane
// for the index (R9-validated). First-index tie-break exact.
#define DPP_ROW_SHR(n) (0x110 | (n))
#define DPP_BCAST15 0x142
#define DPP_BCAST31 0x143

template <int CTRL>
__device__ __forceinline__ float vmin_step(float v) {
    int s = __builtin_amdgcn_update_dpp(0x7149F2CA /* 1e30f */, __float_as_int(v),
                                        CTRL, 0xF, 0xF, false);
    return fminf(v, __int_as_float(s));
}

__device__ __forceinline__ void wave_argmin(float& bv, int& bj) {
    float m = bv;
    m = vmin_step<DPP_ROW_SHR(1)>(m);
    m = vmin_step<DPP_ROW_SHR(2)>(m);
    m = vmin_step<DPP_ROW_SHR(4)>(m);
    m = vmin_step<DPP_ROW_SHR(8)>(m);
    m = vmin_step<DPP_BCAST15>(m);
    m = vmin_step<DPP_BCAST31>(m);
    float g = __int_as_float(__builtin_amdgcn_readlane(__float_as_int(m), 63));
    unsigned long long win = __ballot(bv == g);
    int L = __ffsll((unsigned long long)win) - 1;
    int j = __builtin_amdgcn_readlane(bj, L);
    if (__builtin_popcountll(win) > 1) {   // exact cross-lane tie-break (rare)
        unsigned long long w = win & (win - 1);
        while (w) {
            int l = __ffsll((unsigned long long)w) - 1; w &= w - 1;
            int cj = __builtin_amdgcn_readlane(bj, l);
            j = (cj < j) ? cj : j;
        }
    }
    bv = g; bj = j;
}

#define VC(s) case s: if (lane == ow0) v_r[s] = (v_r[s] + spc_r[s]) - minv; break;

// Assigned-check without LDS: bit sl of owner lane ow's asg mask, via ballot.
#define ASG_CHECK(ow, sl) (__ballot((lane == (ow)) && ((asg >> (sl)) & 1u)) != 0ull)

// Row body (R9 structure): consumes CUR (row I's costs); prefetches row I+2
// into PF2 at start (3-buffer rotation -> ~2 row bodies of latency cover).
#define ROW_BODY(I, CUR, PF2)                                                          \
  {                                                                                    \
    const int i = (I);                                                                 \
    if (i + 2 < NT) {                                                                  \
        const float4* nrow = (const float4*)(costb + (size_t)(i + 2) * NP);            \
        _Pragma("unroll") for (int g = 0; g < 8; ++g) {                                \
            float4 t4 = nrow[g * 64 + lane];                                           \
            PF2[g * 4 + 0] = t4.x; PF2[g * 4 + 1] = t4.y;                              \
            PF2[g * 4 + 2] = t4.z; PF2[g * 4 + 3] = t4.w;                              \
        }                                                                              \
    }                                                                                  \
    unsigned SCm = 0, pathm = 0;                                                       \
    int sr01 = 0;                                                                      \
    /* ---- fast first pop: cur=i, minv=0, u[i]=0 -> red = cost - v exactly ---- */    \
    float bv; int bj;                                                                  \
    {                                                                                  \
        float g0v, g2v, g4v, g6v; int g0j, g2j, g4j, g6j;                              \
        _Pragma("unroll") for (int g = 0; g < 8; g += 2) {                             \
            const int sA = g * 4, sB = sA + 4;                                         \
            const int jA = (g << 8) | lane4, jB = ((g + 1) << 8) | lane4;              \
            float a0 = CUR[sA + 0] - v_r[sA + 0]; spc_r[sA + 0] = a0;                  \
            float a1 = CUR[sA + 1] - v_r[sA + 1]; spc_r[sA + 1] = a1;                  \
            float a2 = CUR[sA + 2] - v_r[sA + 2]; spc_r[sA + 2] = a2;                  \
            float a3 = CUR[sA + 3] - v_r[sA + 3]; spc_r[sA + 3] = a3;                  \
            float b0 = CUR[sB + 0] - v_r[sB + 0]; spc_r[sB + 0] = b0;                  \
            float b1 = CUR[sB + 1] - v_r[sB + 1]; spc_r[sB + 1] = b1;                  \
            float b2 = CUR[sB + 2] - v_r[sB + 2]; spc_r[sB + 2] = b2;                  \
            float b3 = CUR[sB + 3] - v_r[sB + 3]; spc_r[sB + 3] = b3;                  \
            float mA = a0; int qA = jA;                                                \
            if (a1 < mA) { mA = a1; qA = jA + 1; }                                     \
            float mC = a2; int qC = jA + 2;                                            \
            if (a3 < mC) { mC = a3; qC = jA + 3; }                                     \
            if (mC < mA) { mA = mC; qA = qC; }                                         \
            float mB = b0; int qB = jB;                                                \
            if (b1 < mB) { mB = b1; qB = jB + 1; }                                     \
            float mD = b2; int qD = jB + 2;                                            \
            if (b3 < mD) { mD = b3; qD = jB + 3; }                                     \
            if (mD < mB) { mB = mD; qB = qD; }                                         \
            if (mB < mA) { mA = mB; qA = qB; }                                         \
            if (g == 0) { g0v = mA; g0j = qA; }                                        \
            else if (g == 2) { g2v = mA; g2j = qA; }                                   \
            else if (g == 4) { g4v = mA; g4j = qA; }                                   \
            else { g6v = mA; g6j = qA; }                                               \
        }                                                                              \
        if (g2v < g0v) { g0v = g2v; g0j = g2j; }                                       \
        if (g6v < g4v) { g4v = g6v; g4j = g6j; }                                       \
        if (g4v < g0v) { g0v = g4v; g0j = g4j; }                                       \
        bv = g0v; bj = g0j;                                                            \
    }                                                                                  \
    wave_argmin(bv, bj);                                                               \
    float mv = bv; int mj = bj;                                                        \
    int ow0 = (mj >> 2) & 63;                                                          \
    int sl0 = ((mj >> 8) << 2) | (mj & 3);                                             \
    if (lane == ow0) SCm |= (1u << sl0);                                               \
    int npops = 1;                                                                     \
    bool assigned = ASG_CHECK(ow0, sl0);                                               \
    if (assigned) {                                                                    \
        int r = row4col[mj];                                                           \
        /* ---- general shortest-path continuation ---- */                             \
        for (;;) {                                                                     \
            if ((r & 63) == lane) {                                                    \
                if (r < 64) { sr01 |= 1; pm0 = mv; }                                   \
                else        { sr01 |= 2; pm1 = mv; }                                   \
            }                                                                          \
            const int cur = r;                                                         \
            float usel = (cur >= 64) ? u1 : u0;                                        \
            float ucur = __int_as_float(                                               \
                __builtin_amdgcn_readlane(__float_as_int(usel), cur & 63));            \
            const float4* rrow = (const float4*)(costb + (size_t)cur * NP);            \
            _Pragma("unroll") for (int g = 0; g < 8; ++g) {                            \
                float4 t4 = rrow[g * 64 + lane];                                       \
                cr[g * 4 + 0] = t4.x; cr[g * 4 + 1] = t4.y;                            \
                cr[g * 4 + 2] = t4.z; cr[g * 4 + 3] = t4.w;                            \
            }                                                                          \
            bv = BIGF; bj = NP;                                                        \
            _Pragma("unroll") for (int s = 0; s < 32; ++s) {                           \
                float red = ((mv + cr[s]) - ucur) - v_r[s];                            \
                bool notSC = ((SCm >> s) & 1u) == 0u;                                  \
                bool imp = notSC && (red < spc_r[s]);                                  \
                spc_r[s] = imp ? red : spc_r[s];                                       \
                path_r[s] = imp ? cur : path_r[s];                                     \
                pathm = imp ? (pathm | (1u << s)) : pathm;                             \
                float cand = notSC ? spc_r[s] : BIGF;                                  \
                int j = (((s >> 2) << 8) | (s & 3)) | lane4;                           \
                if (cand < bv) { bv = cand; bj = j; }                                  \
            }                                                                          \
            wave_argmin(bv, bj);                                                       \
            mv = bv; mj = bj;                                                          \
            ow0 = (mj >> 2) & 63; sl0 = ((mj >> 8) << 2) | (mj & 3);                   \
            if (lane == ow0) SCm |= (1u << sl0);                                       \
            ++npops;                                                                   \
            assigned = ASG_CHECK(ow0, sl0);                                            \
            if (!assigned) break;                                                      \
            r = row4col[mj];                                                           \
        }                                                                              \
    }                                                                                  \
    const int sink = mj;                                                               \
    const float minv = mv;                                                             \
    /* ---- dual updates (exact reference order) ---- */                               \
    if ((i & 63) == lane) { if (i < 64) u0 = u0 + minv; else u1 = u1 + minv; }         \
    if (sr01 & 1) u0 = (u0 + minv) - pm0;                                              \
    if (sr01 & 2) u1 = (u1 + minv) - pm1;                                              \
    /* sink becomes assigned: register mask mirrors row4col[sink]>=0 */                \
    if (lane == ow0) asg |= (1u << sl0);                                               \
    if (npops == 1) {                                                                  \
        /* SC = {sink}: single-slot v-update, uniform scalar switch */                 \
        switch (sl0) {                                                                 \
            VC(0) VC(1) VC(2) VC(3) VC(4) VC(5) VC(6) VC(7)                            \
            VC(8) VC(9) VC(10) VC(11) VC(12) VC(13) VC(14) VC(15)                      \
            VC(16) VC(17) VC(18) VC(19) VC(20) VC(21) VC(22) VC(23)                    \
            VC(24) VC(25) VC(26) VC(27) VC(28) VC(29) VC(30) VC(31)                    \
        }                                                                              \
        if (lane == 0) { row4col[sink] = i; col4row[i] = sink; }                       \
    } else {                                                                           \
        _Pragma("unroll") for (int s = 0; s < 32; ++s) {                               \
            if ((SCm >> s) & 1u) v_r[s] = (v_r[s] + spc_r[s]) - minv;                  \
        }                                                                              \
        int j = sink;                                                                  \
        while (true) {                                                                 \
            int sl = ((j >> 8) << 2) | (j & 3);                                        \
            int ow = (j >> 2) & 63;                                                    \
            int pv = ((pathm >> 0) & 1u) ? path_r[0] : i;                              \
            _Pragma("unroll") for (int s = 1; s < 32; ++s) {                           \
                int leaf = ((pathm >> s) & 1u) ? path_r[s] : i;                        \
                pv = (sl == s) ? leaf : pv;                                            \
            }                                                                          \
            int ii = __builtin_amdgcn_readlane(pv, ow);                                \
            if (lane == 0) row4col[j] = ii;                                            \
            int nj = col4row[ii];                                                      \
            if (lane == 0) col4row[ii] = j;                                            \
            if (ii == i) break;                                                        \
            j = nj;                                                                    \
        }                                                                              \
    }                                                                                  \
  }

// Phase 2: wave-synchronous JV LSAP. One 64-lane wave per batch.
// Column j: owner lane = (j>>2)&63, slot = ((j>>8)<<2)|(j&3).
__global__ __launch_bounds__(64) void solve_wave(const float* __restrict__ cost,
                                                 int* __restrict__ out) {
    __shared__ int row4col[NP];
    __shared__ int col4row[NT];

    const int lane = threadIdx.x;
    const int lane4 = lane << 2;
    const int b = blockIdx.x;
    const float* costb = cost + (size_t)b * NT * NP;

    float pfA[32], pfB[32], pfC[32], v_r[32], spc_r[32], cr[32];
    int path_r[32];
    unsigned asg = 0;   // per-lane assigned-column bitmask (slot s of this lane)
    float u0 = 0.0f, u1 = 0.0f, pm0 = 0.0f, pm1 = 0.0f;

#pragma unroll
    for (int s = 0; s < 32; ++s) { v_r[s] = 0.0f; path_r[s] = 0; }
    for (int j = lane; j < NP; j += 64) row4col[j] = -1;
    col4row[lane] = -1;
    col4row[lane + 64] = -1;

    {   // prologue: load row 0 -> pfA, row 1 -> pfB
        const float4* r0 = (const float4*)costb;
        const float4* r1 = (const float4*)(costb + NP);
#pragma unroll
        for (int g = 0; g < 8; ++g) {
            float4 t4 = r0[g * 64 + lane];
            pfA[g * 4 + 0] = t4.x; pfA[g * 4 + 1] = t4.y;
            pfA[g * 4 + 2] = t4.z; pfA[g * 4 + 3] = t4.w;
        }
#pragma unroll
        for (int g = 0; g < 8; ++g) {
            float4 t4 = r1[g * 64 + lane];
            pfB[g * 4 + 0] = t4.x; pfB[g * 4 + 1] = t4.y;
            pfB[g * 4 + 2] = t4.z; pfB[g * 4 + 3] = t4.w;
        }
    }

    // 128 rows = 42*3 + 2; 3-buffer rotation, prefetch distance 2.
    for (int it = 0; it < 42; ++it) {
        ROW_BODY(3 * it + 0, pfA, pfC)
        ROW_BODY(3 * it + 1, pfB, pfA)
        ROW_BODY(3 * it + 2, pfC, pfB)
    }
    ROW_BODY(126, pfA, pfC)   // i+2 = 128 -> prefetch skipped
    ROW_BODY(127, pfB, pfA)   // i+2 = 129 -> prefetch skipped

    // output: sort targets by assigned pred index (all distinct)
    for (int t = lane; t < NT; t += 64) {
        int c = col4row[t];
        int rank = 0;
        for (int t2 = 0; t2 < NT; ++t2) rank += (col4row[t2] < c) ? 1 : 0;
        out[(b * 2 + 0) * NT + rank] = c;
        out[(b * 2 + 1) * NT + rank] = t;
    }
}

// Fallback (ws too small): LDS-based block solver computing costs on the fly.
__global__ __launch_bounds__(512) void solve_fallback(const float* __restrict__ ob,
                                                      const float* __restrict__ tb,
                                                      int* __restrict__ out) {
    __shared__ float v[NP], spc[NP];
    __shared__ int path[NP], row4col[NP];
    __shared__ unsigned char SC[NP];
    __shared__ float u[NT];
    __shared__ int col4row[NT];
    __shared__ unsigned char SR[NT];
    __shared__ float rv[8];
    __shared__ int ri[8];
    __shared__ int s_cur, s_sink;
    __shared__ float s_minv;
    __shared__ float px0[NP], py0[NP], px1[NP], py1[NP], pa[NP];
    __shared__ float tx0[NT], ty0[NT], tx1[NT], ty1[NT], ta[NT];

    const int tid = threadIdx.x;
    const int b = blockIdx.x;

    for (int j = tid; j < NP; j += 512) {
        v[j] = 0.0f; row4col[j] = -1;
        float4 o = ((const float4*)ob)[b * NP + j];
        px0[j] = o.x; py0[j] = o.y; px1[j] = o.z; py1[j] = o.w;
        pa[j] = (o.z - o.x) * (o.w - o.y);
    }
    for (int t = tid; t < NT; t += 512) {
        u[t] = 0.0f; col4row[t] = -1;
        float4 g = ((const float4*)tb)[b * NT + t];
        tx0[t] = g.x; ty0[t] = g.y; tx1[t] = g.z; ty1[t] = g.w;
        ta[t] = (g.z - g.x) * (g.w - g.y);
    }
    __syncthreads();

    for (int i = 0; i < NT; ++i) {
        for (int j = tid; j < NP; j += 512) { spc[j] = BIGF; SC[j] = 0; }
        for (int t = tid; t < NT; t += 512) SR[t] = 0;
        if (tid == 0) { s_cur = i; s_minv = 0.0f; s_sink = -1; }
        __syncthreads();

        while (s_sink < 0) {
            const int cur = s_cur;
            const float minv = s_minv;
            if (tid == 0) SR[cur] = 1;
            const float ucur = u[cur];
            float c0 = tx0[cur], c1 = ty0[cur], c2 = tx1[cur], c3 = ty1[cur], ca = ta[cur];
            float bv = BIGF;
            int bi = NP;
            for (int k = 0; k < NP / 512; ++k) {
                int j = tid + k * 512;
                float cj = box_cost(px0[j], py0[j], px1[j], py1[j], c0, c1, c2, c3, pa[j], ca);
                float cand;
                if (!SC[j]) {
                    float red = ((minv + cj) - ucur) - v[j];
                    if (red < spc[j]) { spc[j] = red; path[j] = cur; }
                    cand = spc[j];
                } else {
                    cand = BIGF;
                }
                if (cand < bv || (cand == bv && j < bi)) { bv = cand; bi = j; }
            }
            for (int off = 32; off >= 1; off >>= 1) {
                float ov = __shfl_xor(bv, off);
                int oi = __shfl_xor(bi, off);
                if (ov < bv || (ov == bv && oi < bi)) { bv = ov; bi = oi; }
            }
            if ((tid & 63) == 0) { rv[tid >> 6] = bv; ri[tid >> 6] = bi; }
            __syncthreads();
            if (tid == 0) {
                float mvv = rv[0]; int mjj = ri[0];
                for (int w = 1; w < 8; ++w)
                    if (rv[w] < mvv || (rv[w] == mvv && ri[w] < mjj)) { mvv = rv[w]; mjj = ri[w]; }
                s_minv = mvv;
                SC[mjj] = 1;
                int rr = row4col[mjj];
                if (rr < 0) s_sink = mjj; else s_cur = rr;
            }
            __syncthreads();
        }

        const float minv = s_minv;
        const int sink = s_sink;
        for (int j = tid; j < NP; j += 512) if (SC[j]) v[j] = (v[j] + spc[j]) - minv;
        for (int t = tid; t < NT; t += 512) {
            if (t == i) u[t] = u[t] + minv;
            else if (SR[t]) u[t] = (u[t] + minv) - spc[col4row[t]];
        }
        __syncthreads();
        if (tid == 0) {
            int j = sink;
            while (true) {
                int ii = path[j];
                row4col[j] = ii;
                int nj = col4row[ii];
                col4row[ii] = j;
                if (ii == i) break;
                j = nj;
            }
        }
        __syncthreads();
    }

    if (tid < NT) {
        int c = col4row[tid];
        int rank = 0;
        for (int t2 = 0; t2 < NT; ++t2) rank += (col4row[t2] < c) ? 1 : 0;
        out[(b * 2 + 0) * NT + rank] = c;
        out[(b * 2 + 1) * NT + rank] = tid;
    }
}

extern "C" void kernel_launch(void* const* d_in, const int* in_sizes, int n_in,
                              void* d_out, int out_size, void* d_ws, size_t ws_size,
                              hipStream_t stream) {
    const float* ob = (const float*)d_in[0];   // [32, 2048, 4] f32
    const float* tb = (const float*)d_in[1];   // [32, 128, 4] f32
    int* out = (int*)d_out;                    // [32, 2, 128] int32

    const size_t need = (size_t)NB * NT * NP * sizeof(float);  // 32 MB
    if (ws_size >= need) {
        float* cost = (float*)d_ws;
        cost_kernel<<<(NB * NT * NP) / 256, 256, 0, stream>>>(ob, tb, cost);
        solve_wave<<<NB, 64, 0, stream>>>(cost, out);
    } else {
        solve_fallback<<<NB, 512, 0, stream>>>(ob, tb, out);
    }
}